// Round 1
// baseline (902.927 us; speedup 1.0000x reference)
//
#include <hip/hip_runtime.h>
#include <math.h>

#define D_MODEL 1024
#define MEM_HEADS 4
#define KNN 32
#define KEY_DIM 288
#define VALUE_DIM 512
#define Q_RANK 512
#define NUM_BUCKETS 18
#define BUCKET_DIM 16
#define NTOK 2048                      // BATCH * SEQ
#define ROWS (NTOK * MEM_HEADS)        // 8192
#define QDIM (MEM_HEADS * KEY_DIM)     // 1152

// ---------------------------------------------------------------------------
// GEMM: C[M,N] = A[M,K] @ B[N,K]^T (+ bias[N]).  A,B row-major, K contiguous.
// BM=BN=64, BK=16, 256 threads, 4x4 micro-tile. All dims divide evenly here.
// ---------------------------------------------------------------------------
__global__ __launch_bounds__(256) void gemm_nt_kernel(
    const float* __restrict__ A, const float* __restrict__ B,
    const float* __restrict__ bias, float* __restrict__ C,
    int M, int N, int K)
{
    // +4 pad keeps float4 alignment (68*4 B = 272 ≡ 0 mod 16) and breaks the
    // 4-way store conflict down to 2-way (free on CDNA4).
    __shared__ __align__(16) float As[16][68];
    __shared__ __align__(16) float Bs[16][68];

    const int tid  = threadIdx.x;
    const int bm   = blockIdx.y * 64;
    const int bn   = blockIdx.x * 64;
    const int lrow = tid >> 2;          // 0..63 tile row for loading
    const int lk   = (tid & 3) * 4;     // k offset 0,4,8,12
    const int ty   = tid >> 4;          // 0..15
    const int tx   = tid & 15;          // 0..15

    const float* Aptr = A + (size_t)(bm + lrow) * K + lk;
    const float* Bptr = B + (size_t)(bn + lrow) * K + lk;

    float acc[4][4];
#pragma unroll
    for (int i = 0; i < 4; ++i)
#pragma unroll
        for (int j = 0; j < 4; ++j) acc[i][j] = 0.f;

    for (int k0 = 0; k0 < K; k0 += 16) {
        const float4 a4 = *(const float4*)(Aptr + k0);
        const float4 b4 = *(const float4*)(Bptr + k0);
        __syncthreads();
        As[lk + 0][lrow] = a4.x; As[lk + 1][lrow] = a4.y;
        As[lk + 2][lrow] = a4.z; As[lk + 3][lrow] = a4.w;
        Bs[lk + 0][lrow] = b4.x; Bs[lk + 1][lrow] = b4.y;
        Bs[lk + 2][lrow] = b4.z; Bs[lk + 3][lrow] = b4.w;
        __syncthreads();
#pragma unroll
        for (int kk = 0; kk < 16; ++kk) {
            const float4 af = *(const float4*)&As[kk][ty * 4];
            const float4 bf = *(const float4*)&Bs[kk][tx * 4];
            const float a[4] = {af.x, af.y, af.z, af.w};
            const float b[4] = {bf.x, bf.y, bf.z, bf.w};
#pragma unroll
            for (int i = 0; i < 4; ++i)
#pragma unroll
                for (int j = 0; j < 4; ++j)
                    acc[i][j] += a[i] * b[j];
        }
    }

    float4 bb = {0.f, 0.f, 0.f, 0.f};
    if (bias) bb = *(const float4*)(bias + bn + tx * 4);
#pragma unroll
    for (int i = 0; i < 4; ++i) {
        float4 o;
        o.x = acc[i][0] + bb.x; o.y = acc[i][1] + bb.y;
        o.z = acc[i][2] + bb.z; o.w = acc[i][3] + bb.w;
        *(float4*)(C + (size_t)(bm + ty * 4 + i) * N + bn + tx * 4) = o;
    }
}

// ---------------------------------------------------------------------------
// Trellis beam search. One thread per row (row = token*4 + head), 64/block.
// Beam kept in LDS with [entry][lane] layout -> every LDS access lands 2
// lanes/bank (free). Stable two-pointer merge == jax.lax.top_k tie-breaking
// (lower concat index wins; A-half = old beam precedes B-half = old+delta).
// Softmax: penalty 0 always survives => softmax(best - pen) == exp(-pen)/Z.
// ---------------------------------------------------------------------------
__global__ __launch_bounds__(64) void trellis_kernel(
    const float* __restrict__ q, const float* __restrict__ keys,
    float* __restrict__ sc_out, int* __restrict__ idx_out)
{
    __shared__ float s_keys[MEM_HEADS * NUM_BUCKETS * 2 * BUCKET_DIM]; // 2304
    __shared__ float penB[2][KNN][64];
    __shared__ int   mskB[2][KNN][64];
    __shared__ float dlt[NUM_BUCKETS][64];

    const int tid = threadIdx.x;
    for (int i = tid; i < MEM_HEADS * NUM_BUCKETS * 2 * BUCKET_DIM; i += 64)
        s_keys[i] = keys[i];
    __syncthreads();

    const int r = blockIdx.x * 64 + tid;
    const int h = r & 3;
    const float* qr = q + (size_t)r * KEY_DIM;

    int code = 0;
    for (int m = 0; m < NUM_BUCKETS; ++m) {
        const float* km = s_keys + h * (NUM_BUCKETS * 32) + m * 32;
        float s0 = 0.f, s1 = 0.f;
#pragma unroll
        for (int d = 0; d < BUCKET_DIM; ++d) {
            const float qv = qr[m * BUCKET_DIM + d];
            s0 += qv * km[d];
            s1 += qv * km[16 + d];
        }
        dlt[m][tid] = fabsf(s0 - s1);
        if (s1 > s0) code |= (1 << m);
    }

    penB[0][0][tid] = 0.f;
    mskB[0][0][tid] = 0;
    int nb = 1, cur = 0;
    for (int t = 0; t < NUM_BUCKETS; ++t) {
        const float d = dlt[t][tid];
        const int nk = min(KNN, nb * 2);
        const int nxt = cur ^ 1;
        int i = 0, j = 0;
        for (int o = 0; o < nk; ++o) {
            const float pa = (i < nb) ? penB[cur][i][tid] : 3.4e38f;
            const float pb = (j < nb) ? (penB[cur][j][tid] + d) : 3.4e38f;
            if (pa <= pb) {              // tie -> A side, matches top_k
                penB[nxt][o][tid] = pa;
                mskB[nxt][o][tid] = mskB[cur][i][tid];
                ++i;
            } else {
                penB[nxt][o][tid] = pb;
                mskB[nxt][o][tid] = mskB[cur][j][tid] ^ (1 << t);
                ++j;
            }
        }
        nb = nk;
        cur = nxt;
    }

    float e[KNN];
    float Z = 0.f;
#pragma unroll
    for (int i = 0; i < KNN; ++i) {
        e[i] = expf(-penB[cur][i][tid]);
        Z += e[i];
    }
    const float inv = 1.0f / Z;
#pragma unroll
    for (int i = 0; i < KNN; ++i) {
        sc_out[(size_t)r * KNN + i]  = e[i] * inv;
        idx_out[(size_t)r * KNN + i] = code ^ mskB[cur][i][tid];
    }
}

// ---------------------------------------------------------------------------
// Gather + embedding-bag: y[n,:] = sum_k score[n,k] * values[idx[n,k],:]
// One block (128 threads = 2 waves) per token, float4 per lane (512 dims).
// HBM-bound: 512 MB of random 2KB-row reads.
// ---------------------------------------------------------------------------
__global__ __launch_bounds__(128) void gather_kernel(
    const float* __restrict__ sc, const int* __restrict__ idx,
    const float* __restrict__ values, float* __restrict__ y)
{
    __shared__ float s_s[MEM_HEADS * KNN];
    __shared__ int   s_i[MEM_HEADS * KNN];
    const int n = blockIdx.x;
    const int t = threadIdx.x;          // 0..127
    s_s[t] = sc[(size_t)n * 128 + t];
    s_i[t] = idx[(size_t)n * 128 + t];
    __syncthreads();

    float4 acc = {0.f, 0.f, 0.f, 0.f};
#pragma unroll 4
    for (int k = 0; k < 128; ++k) {
        const float4 v = *(const float4*)(values + (size_t)s_i[k] * VALUE_DIM + t * 4);
        const float w = s_s[k];
        acc.x += w * v.x; acc.y += w * v.y;
        acc.z += w * v.z; acc.w += w * v.w;
    }
    *(float4*)(y + (size_t)n * VALUE_DIM + t * 4) = acc;
}

// ---------------------------------------------------------------------------
extern "C" void kernel_launch(void* const* d_in, const int* in_sizes, int n_in,
                              void* d_out, int out_size, void* d_ws, size_t ws_size,
                              hipStream_t stream)
{
    (void)in_sizes; (void)n_in; (void)out_size; (void)ws_size;
    const float* x      = (const float*)d_in[0];
    const float* keys   = (const float*)d_in[1];
    const float* qd_w   = (const float*)d_in[2];
    const float* qd_b   = (const float*)d_in[3];
    const float* qu_w   = (const float*)d_in[4];
    const float* values = (const float*)d_in[5];
    const float* vp_w   = (const float*)d_in[6];
    float* out = (float*)d_out;

    // workspace layout (floats / ints), ~20 MB total
    float* q_mid = (float*)d_ws;                       // 2048*512
    float* q     = q_mid + (size_t)NTOK * Q_RANK;      // 2048*1152
    float* sc    = q + (size_t)NTOK * QDIM;            // 8192*32
    int*   idx   = (int*)(sc + (size_t)ROWS * KNN);    // 8192*32
    float* y     = (float*)(idx + (size_t)ROWS * KNN); // 2048*512

    // q_mid = x @ qd_w^T + qd_b
    gemm_nt_kernel<<<dim3(Q_RANK / 64, NTOK / 64), 256, 0, stream>>>(
        x, qd_w, qd_b, q_mid, NTOK, Q_RANK, D_MODEL);
    // q = q_mid @ qu_w^T
    gemm_nt_kernel<<<dim3(QDIM / 64, NTOK / 64), 256, 0, stream>>>(
        q_mid, qu_w, nullptr, q, NTOK, QDIM, Q_RANK);
    // beam search -> softmaxed scores + indices
    trellis_kernel<<<ROWS / 64, 64, 0, stream>>>(q, keys, sc, idx);
    // weighted gather -> y [2048, 512]
    gather_kernel<<<NTOK, 128, 0, stream>>>(sc, idx, values, y);
    // out = y @ vp_w^T
    gemm_nt_kernel<<<dim3(D_MODEL / 64, NTOK / 64), 256, 0, stream>>>(
        y, vp_w, nullptr, out, NTOK, D_MODEL, VALUE_DIM);
}

// Round 3
// 871.317 us; speedup vs baseline: 1.0363x; 1.0363x over previous
//
#include <hip/hip_runtime.h>
#include <math.h>

#define D_MODEL 1024
#define MEM_HEADS 4
#define KNN 32
#define KEY_DIM 288
#define VALUE_DIM 512
#define Q_RANK 512
#define NUM_BUCKETS 18
#define BUCKET_DIM 16
#define NTOK 2048                      // BATCH * SEQ
#define ROWS (NTOK * MEM_HEADS)        // 8192
#define QDIM (MEM_HEADS * KEY_DIM)     // 1152

typedef __attribute__((ext_vector_type(8))) short bfrag;   // 8 bf16 halves (4 VGPRs)
typedef __attribute__((ext_vector_type(4))) float f32x4;   // MFMA C/D frag

__device__ __forceinline__ unsigned short f2bf(float x) {  // RNE fp32->bf16
    unsigned int u = __builtin_bit_cast(unsigned int, x);
    u += 0x7FFFu + ((u >> 16) & 1u);
    return (unsigned short)(u >> 16);
}
__device__ __forceinline__ float bf2f(unsigned short h) {
    unsigned int u = ((unsigned int)h) << 16;
    return __builtin_bit_cast(float, u);
}

// ---------------------------------------------------------------------------
// Split-bf16 MFMA GEMM: C[M,N] = A[M,K] @ B[N,K]^T (+bias). fp32 in/out.
// MODE=3 (bf16x6): a=a0+a1+a2, products {00,01,10,11,02,20}; dropped terms
//   < 4*2^-27 per product -> fp32-equivalent. REQUIRED for the q path: the
//   trellis compares penalties at ~1e-5 separation; bf16x3's 2^-18 error
//   flipped near-ties (round-2 failure, absmax 6.2e-3).
// MODE=2 (bf16x3): products {00,01,10}, ~1e-4 output error. OK for GEMM3
//   only (no decisions downstream).
// 64x64 tile, BK=32, 256 threads; 4 waves 2x2, each wave 2x2 16x16x32 tiles.
// 64-tile (not 128) so GEMM1's grid is 256 blocks, not 64 (grid fill).
// LDS row stride 40 halves; frag layouts per m89/m91: A[m=lane&15][k=quad*8+j],
// B[n=lane&15][k], C/D col=lane&15,row=quad*4+reg.
// ---------------------------------------------------------------------------
#define LSTR 40
template<int MODE>
__global__ __launch_bounds__(256) void gemm_nt_split(
    const float* __restrict__ A, const float* __restrict__ B,
    const float* __restrict__ bias, float* __restrict__ C,
    int M, int N, int K)
{
    __shared__ __align__(16) unsigned short As[MODE][64][LSTR];
    __shared__ __align__(16) unsigned short Bs[MODE][64][LSTR];

    const int tid  = threadIdx.x;
    const int bm   = blockIdx.y * 64;
    const int bn   = blockIdx.x * 64;
    const int wave = tid >> 6;
    const int lane = tid & 63;
    const int wr   = wave & 1;          // wave m-half (32 rows)
    const int wc   = wave >> 1;         // wave n-half (32 cols)
    const int l15  = lane & 15;
    const int quad = lane >> 4;

    const int sr = tid >> 2;            // staging row 0..63
    const int sg = tid & 3;             // staging 8-float segment

    f32x4 acc[2][2];
#pragma unroll
    for (int i = 0; i < 2; ++i)
#pragma unroll
        for (int j = 0; j < 2; ++j) acc[i][j] = (f32x4){0.f, 0.f, 0.f, 0.f};

    const float* Ap = A + (size_t)(bm + sr) * K + sg * 8;
    const float* Bp = B + (size_t)(bn + sr) * K + sg * 8;

    for (int k0 = 0; k0 < K; k0 += 32) {
        const float4 a0 = *(const float4*)(Ap + k0);
        const float4 a1 = *(const float4*)(Ap + k0 + 4);
        const float4 b0 = *(const float4*)(Bp + k0);
        const float4 b1 = *(const float4*)(Bp + k0 + 4);

        __syncthreads();   // prior chunk's frag reads done
        {
            const float va[8] = {a0.x,a0.y,a0.z,a0.w, a1.x,a1.y,a1.z,a1.w};
            const float vb[8] = {b0.x,b0.y,b0.z,b0.w, b1.x,b1.y,b1.z,b1.w};
            bfrag ha[MODE], hb[MODE];
#pragma unroll
            for (int i = 0; i < 8; ++i) {
                float xa = va[i], xb = vb[i];
#pragma unroll
                for (int s = 0; s < MODE; ++s) {
                    const unsigned short sa = f2bf(xa), sb = f2bf(xb);
                    ha[s][i] = (short)sa; hb[s][i] = (short)sb;
                    xa -= bf2f(sa);       xb -= bf2f(sb);
                }
            }
#pragma unroll
            for (int s = 0; s < MODE; ++s) {
                *(bfrag*)&As[s][sr][sg * 8] = ha[s];
                *(bfrag*)&Bs[s][sr][sg * 8] = hb[s];
            }
        }
        __syncthreads();   // tiles visible

        bfrag af[MODE][2], bf[MODE][2];
#pragma unroll
        for (int t = 0; t < 2; ++t) {
            const int mr = wr * 32 + t * 16 + l15;
            const int nr = wc * 32 + t * 16 + l15;
#pragma unroll
            for (int s = 0; s < MODE; ++s) {
                af[s][t] = *(const bfrag*)&As[s][mr][quad * 8];
                bf[s][t] = *(const bfrag*)&Bs[s][nr][quad * 8];
            }
        }
#pragma unroll
        for (int mt = 0; mt < 2; ++mt)
#pragma unroll
            for (int nt = 0; nt < 2; ++nt) {
                f32x4 c = acc[mt][nt];
                c = __builtin_amdgcn_mfma_f32_16x16x32_bf16(af[0][mt], bf[0][nt], c, 0, 0, 0);
                c = __builtin_amdgcn_mfma_f32_16x16x32_bf16(af[0][mt], bf[1][nt], c, 0, 0, 0);
                c = __builtin_amdgcn_mfma_f32_16x16x32_bf16(af[1][mt], bf[0][nt], c, 0, 0, 0);
                if (MODE == 3) {
                    c = __builtin_amdgcn_mfma_f32_16x16x32_bf16(af[1][mt], bf[1][nt], c, 0, 0, 0);
                    c = __builtin_amdgcn_mfma_f32_16x16x32_bf16(af[0][mt], bf[2][nt], c, 0, 0, 0);
                    c = __builtin_amdgcn_mfma_f32_16x16x32_bf16(af[2][mt], bf[0][nt], c, 0, 0, 0);
                }
                acc[mt][nt] = c;
            }
    }

    // epilogue: C/D frag (col=l15, row=quad*4+g) -> row-major C (+bias)
#pragma unroll
    for (int nt = 0; nt < 2; ++nt) {
        const int col = bn + wc * 32 + nt * 16 + l15;
        const float bv = bias ? bias[col] : 0.f;
#pragma unroll
        for (int mt = 0; mt < 2; ++mt) {
            const int rowb = bm + wr * 32 + mt * 16 + quad * 4;
#pragma unroll
            for (int g = 0; g < 4; ++g)
                C[(size_t)(rowb + g) * N + col] = acc[mt][nt][g] + bv;
        }
    }
}

// ---------------------------------------------------------------------------
// Trellis beam search — logic IDENTICAL to the round-1 passing kernel
// (arithmetic order unchanged; dlt in registers, float4 q loads).
// Stable two-pointer merge == jax.lax.top_k tie-break (A-side on ties).
// Softmax: penalty 0 always survives => softmax(best - pen) == exp(-pen)/Z.
// ---------------------------------------------------------------------------
__global__ __launch_bounds__(64) void trellis_kernel(
    const float* __restrict__ q, const float* __restrict__ keys,
    float* __restrict__ sc_out, int* __restrict__ idx_out)
{
    __shared__ float s_keys[MEM_HEADS * NUM_BUCKETS * 2 * BUCKET_DIM]; // 2304
    __shared__ float penB[2][KNN][64];
    __shared__ int   mskB[2][KNN][64];

    const int tid = threadIdx.x;
    for (int i = tid; i < MEM_HEADS * NUM_BUCKETS * 2 * BUCKET_DIM; i += 64)
        s_keys[i] = keys[i];
    __syncthreads();

    const int r = blockIdx.x * 64 + tid;
    const int h = r & 3;
    const float* qr = q + (size_t)r * KEY_DIM;

    float dlt[NUM_BUCKETS];
    int code = 0;
#pragma unroll
    for (int m = 0; m < NUM_BUCKETS; ++m) {
        const float* km = s_keys + h * (NUM_BUCKETS * 32) + m * 32;
        const float4 q0 = *(const float4*)(qr + m * BUCKET_DIM);
        const float4 q1 = *(const float4*)(qr + m * BUCKET_DIM + 4);
        const float4 q2 = *(const float4*)(qr + m * BUCKET_DIM + 8);
        const float4 q3 = *(const float4*)(qr + m * BUCKET_DIM + 12);
        const float qv[16] = {q0.x,q0.y,q0.z,q0.w, q1.x,q1.y,q1.z,q1.w,
                              q2.x,q2.y,q2.z,q2.w, q3.x,q3.y,q3.z,q3.w};
        float s0 = 0.f, s1 = 0.f;
#pragma unroll
        for (int d = 0; d < BUCKET_DIM; ++d) {
            s0 += qv[d] * km[d];
            s1 += qv[d] * km[16 + d];
        }
        dlt[m] = fabsf(s0 - s1);
        if (s1 > s0) code |= (1 << m);
    }

    penB[0][0][tid] = 0.f;
    mskB[0][0][tid] = 0;
    int nb = 1, cur = 0;
#pragma unroll
    for (int t = 0; t < NUM_BUCKETS; ++t) {
        const float d = dlt[t];
        const int nk = min(KNN, nb * 2);
        const int nxt = cur ^ 1;
        int i = 0, j = 0;
        for (int o = 0; o < nk; ++o) {
            const float pa = (i < nb) ? penB[cur][i][tid] : 3.4e38f;
            const float pb = (j < nb) ? (penB[cur][j][tid] + d) : 3.4e38f;
            if (pa <= pb) {              // tie -> A side, matches top_k
                penB[nxt][o][tid] = pa;
                mskB[nxt][o][tid] = mskB[cur][i][tid];
                ++i;
            } else {
                penB[nxt][o][tid] = pb;
                mskB[nxt][o][tid] = mskB[cur][j][tid] ^ (1 << t);
                ++j;
            }
        }
        nb = nk;
        cur = nxt;
    }

    float e[KNN];
    float Z = 0.f;
#pragma unroll
    for (int i = 0; i < KNN; ++i) {
        e[i] = expf(-penB[cur][i][tid]);
        Z += e[i];
    }
    const float inv = 1.0f / Z;
#pragma unroll
    for (int i = 0; i < KNN; ++i) {
        sc_out[(size_t)r * KNN + i]  = e[i] * inv;
        idx_out[(size_t)r * KNN + i] = code ^ mskB[cur][i][tid];
    }
}

// ---------------------------------------------------------------------------
// Gather + embedding-bag: y[n,:] = sum_k score[n,k] * values[idx[n,k],:]
// One block (128 threads) per token; unroll 8 keeps ~8 float4 loads in
// flight per lane. HBM-bound: ~512 MB of random 2KB-row reads.
// ---------------------------------------------------------------------------
__global__ __launch_bounds__(128) void gather_kernel(
    const float* __restrict__ sc, const int* __restrict__ idx,
    const float* __restrict__ values, float* __restrict__ y)
{
    __shared__ float s_s[MEM_HEADS * KNN];
    __shared__ int   s_i[MEM_HEADS * KNN];
    const int n = blockIdx.x;
    const int t = threadIdx.x;          // 0..127
    s_s[t] = sc[(size_t)n * 128 + t];
    s_i[t] = idx[(size_t)n * 128 + t];
    __syncthreads();

    float4 acc = {0.f, 0.f, 0.f, 0.f};
#pragma unroll 8
    for (int k = 0; k < 128; ++k) {
        const float4 v = *(const float4*)(values + (size_t)s_i[k] * VALUE_DIM + t * 4);
        const float w = s_s[k];
        acc.x += w * v.x; acc.y += w * v.y;
        acc.z += w * v.z; acc.w += w * v.w;
    }
    *(float4*)(y + (size_t)n * VALUE_DIM + t * 4) = acc;
}

// ---------------------------------------------------------------------------
extern "C" void kernel_launch(void* const* d_in, const int* in_sizes, int n_in,
                              void* d_out, int out_size, void* d_ws, size_t ws_size,
                              hipStream_t stream)
{
    (void)in_sizes; (void)n_in; (void)out_size; (void)ws_size;
    const float* x      = (const float*)d_in[0];
    const float* keys   = (const float*)d_in[1];
    const float* qd_w   = (const float*)d_in[2];
    const float* qd_b   = (const float*)d_in[3];
    const float* qu_w   = (const float*)d_in[4];
    const float* values = (const float*)d_in[5];
    const float* vp_w   = (const float*)d_in[6];
    float* out = (float*)d_out;

    float* q_mid = (float*)d_ws;                       // 2048*512
    float* q     = q_mid + (size_t)NTOK * Q_RANK;      // 2048*1152
    float* sc    = q + (size_t)NTOK * QDIM;            // 8192*32
    int*   idx   = (int*)(sc + (size_t)ROWS * KNN);    // 8192*32
    float* y     = (float*)(idx + (size_t)ROWS * KNN); // 2048*512

    // q_mid = x @ qd_w^T + qd_b    [2048,1024]@[512,1024]^T  (fp32-equiv)
    gemm_nt_split<3><<<dim3(Q_RANK / 64, NTOK / 64), 256, 0, stream>>>(
        x, qd_w, qd_b, q_mid, NTOK, Q_RANK, D_MODEL);
    // q = q_mid @ qu_w^T           [2048,512]@[1152,512]^T   (fp32-equiv)
    gemm_nt_split<3><<<dim3(QDIM / 64, NTOK / 64), 256, 0, stream>>>(
        q_mid, qu_w, nullptr, q, NTOK, QDIM, Q_RANK);
    // beam search -> softmaxed scores + indices
    trellis_kernel<<<ROWS / 64, 64, 0, stream>>>(q, keys, sc, idx);
    // weighted gather -> y [2048, 512]
    gather_kernel<<<NTOK, 128, 0, stream>>>(sc, idx, values, y);
    // out = y @ vp_w^T             [2048,512]@[1024,512]^T   (bf16x3 ok)
    gemm_nt_split<2><<<dim3(D_MODEL / 64, NTOK / 64), 256, 0, stream>>>(
        y, vp_w, nullptr, out, NTOK, D_MODEL, VALUE_DIM);
}